// Round 3
// baseline (407.309 us; speedup 1.0000x reference)
//
#include <hip/hip_runtime.h>

#define IN_CH 128
#define NEG_SLOPE 0.2f

// ---------------- feat = x @ W  (fp32 vector GEMM, W in LDS) ----------------
// Each thread: 2 rows x 4 cols. Block 256 -> 16 rows. grid = N/16 = 3125.
__global__ __launch_bounds__(256) void k_gemm(const float* __restrict__ x,
                                              const float* __restrict__ W,
                                              float* __restrict__ feat) {
    __shared__ float Wl[128 * 128];
#pragma unroll
    for (int i = 0; i < 16; ++i) {
        ((float4*)Wl)[threadIdx.x + 256 * i] = ((const float4*)W)[threadIdx.x + 256 * i];
    }
    __syncthreads();
    int grp = threadIdx.x >> 5;
    int c4 = (threadIdx.x & 31) * 4;
    int r0 = blockIdx.x * 16 + grp * 2;
    const float* xa = x + (size_t)r0 * 128;
    const float* xb = xa + 128;
    float4 acc0 = {0.f, 0.f, 0.f, 0.f};
    float4 acc1 = {0.f, 0.f, 0.f, 0.f};
    for (int k8 = 0; k8 < 128; k8 += 8) {
        float4 a0 = *(const float4*)(xa + k8);
        float4 a1 = *(const float4*)(xa + k8 + 4);
        float4 b0 = *(const float4*)(xb + k8);
        float4 b1 = *(const float4*)(xb + k8 + 4);
        float av[8] = {a0.x, a0.y, a0.z, a0.w, a1.x, a1.y, a1.z, a1.w};
        float bv[8] = {b0.x, b0.y, b0.z, b0.w, b1.x, b1.y, b1.z, b1.w};
#pragma unroll
        for (int j = 0; j < 8; ++j) {
            float4 wv = *(const float4*)(Wl + (k8 + j) * 128 + c4);
            acc0.x += av[j] * wv.x; acc0.y += av[j] * wv.y;
            acc0.z += av[j] * wv.z; acc0.w += av[j] * wv.w;
            acc1.x += bv[j] * wv.x; acc1.y += bv[j] * wv.y;
            acc1.z += bv[j] * wv.z; acc1.w += bv[j] * wv.w;
        }
    }
    *(float4*)(feat + (size_t)r0 * 128 + c4) = acc0;
    *(float4*)(feat + (size_t)(r0 + 1) * 128 + c4) = acc1;
}

// ---------------- el/er: per-(node,head) dot with attn vectors ----------------
__global__ void k_elr(const float* __restrict__ feat,
                      const float* __restrict__ attn_l,
                      const float* __restrict__ attn_r,
                      float* __restrict__ el, float* __restrict__ er, int n4) {
    int idx = blockIdx.x * 256 + threadIdx.x;
    if (idx >= n4) return;
    int n = idx >> 2, h = idx & 3;
    const float4* f4 = (const float4*)(feat + (size_t)n * 128 + h * 32);
    const float4* al = (const float4*)(attn_l + h * 32);
    const float4* ar = (const float4*)(attn_r + h * 32);
    float sl = 0.f, sr = 0.f;
#pragma unroll
    for (int j = 0; j < 8; ++j) {
        float4 fv = f4[j];
        float4 lv = al[j];
        float4 rv = ar[j];
        sl += fv.x * lv.x + fv.y * lv.y + fv.z * lv.z + fv.w * lv.w;
        sr += fv.x * rv.x + fv.y * rv.y + fv.z * rv.z + fv.w * rv.w;
    }
    el[idx] = sl;
    er[idx] = sr;
}

// ---------------- CSR build: histogram -> scan -> scatter ----------------
__global__ void k_deg(const int* __restrict__ dst, int* __restrict__ deg, int E) {
    int e = blockIdx.x * 256 + threadIdx.x;
    if (e < E) atomicAdd(&deg[dst[e]], 1);
}

// Single-block exclusive scan of deg[N] -> rowstart[N+1], cursor[N].
__global__ __launch_bounds__(1024) void k_scan(const int* __restrict__ deg,
                                               int* __restrict__ rowstart,
                                               int* __restrict__ cursor, int N) {
    const int T = 1024;
    int t = threadIdx.x;
    int CH = (N + T - 1) / T;               // 49
    int base = t * CH;
    int sum = 0;
    for (int i = 0; i < CH; ++i) {
        int id = base + i;
        if (id < N) sum += deg[id];
    }
    __shared__ int ps[T];
    ps[t] = sum;
    __syncthreads();
    for (int off = 1; off < T; off <<= 1) {
        int v = (t >= off) ? ps[t - off] : 0;
        __syncthreads();
        ps[t] += v;
        __syncthreads();
    }
    int run = (t == 0) ? 0 : ps[t - 1];
    for (int i = 0; i < CH; ++i) {
        int id = base + i;
        if (id < N) {
            rowstart[id] = run;
            cursor[id] = run;
            run += deg[id];
        }
    }
    if (t == 0) rowstart[N] = ps[T - 1];
}

__global__ void k_scatter(const int* __restrict__ src, const int* __restrict__ dst,
                          int* __restrict__ cursor, int* __restrict__ esrc, int E) {
    int e = blockIdx.x * 256 + threadIdx.x;
    if (e >= E) return;
    int p = atomicAdd(&cursor[dst[e]], 1);
    esrc[p] = src[e];
}

// ---------------- fused per-node softmax + aggregation (no atomics) ----------------
// One 64-lane wave per node. lane = 32*half + d. Single edge loop accumulates
// per-head exp-sums s_h and unnormalized per-head feature sums a_h; final
// out[n,d] = sum_h a_h * (0.25/s_h) + mean_h bias[h,d].
__global__ __launch_bounds__(256) void k_node(const int* __restrict__ rowstart,
                                              const int* __restrict__ esrc,
                                              const float* __restrict__ el,
                                              const float* __restrict__ er,
                                              const float* __restrict__ feat,
                                              const float* __restrict__ bias,
                                              float* __restrict__ out, int N) {
    int n = blockIdx.x * 4 + (threadIdx.x >> 6);
    if (n >= N) return;
    int lane = threadIdx.x & 63;
    int d = lane & 31;
    int half = lane >> 5;
    int row0 = rowstart[n], row1 = rowstart[n + 1];
    const float* erp = er + (size_t)n * 4;
    float er0 = erp[0], er1 = erp[1], er2 = erp[2], er3 = erp[3];
    float s0 = 0.f, s1 = 0.f, s2 = 0.f, s3 = 0.f;
    float a0 = 0.f, a1 = 0.f, a2 = 0.f, a3 = 0.f;
    for (int j = row0 + half; j < row1; j += 2) {
        int sn = esrc[j];
        const float* elp = el + (size_t)sn * 4;
        float t0 = elp[0] + er0;
        float t1 = elp[1] + er1;
        float t2 = elp[2] + er2;
        float t3 = elp[3] + er3;
        float e0 = __expf(t0 > 0.f ? t0 : NEG_SLOPE * t0);
        float e1 = __expf(t1 > 0.f ? t1 : NEG_SLOPE * t1);
        float e2 = __expf(t2 > 0.f ? t2 : NEG_SLOPE * t2);
        float e3 = __expf(t3 > 0.f ? t3 : NEG_SLOPE * t3);
        s0 += e0; s1 += e1; s2 += e2; s3 += e3;
        const float* f = feat + (size_t)sn * 128 + d;
        a0 += e0 * f[0];
        a1 += e1 * f[32];
        a2 += e2 * f[64];
        a3 += e3 * f[96];
    }
    // combine the two halves (edge parity split)
    s0 += __shfl_xor(s0, 32); s1 += __shfl_xor(s1, 32);
    s2 += __shfl_xor(s2, 32); s3 += __shfl_xor(s3, 32);
    a0 += __shfl_xor(a0, 32); a1 += __shfl_xor(a1, 32);
    a2 += __shfl_xor(a2, 32); a3 += __shfl_xor(a3, 32);
    if (lane < 32) {
        float r = a0 * (0.25f / s0) + a1 * (0.25f / s1) +
                  a2 * (0.25f / s2) + a3 * (0.25f / s3);
        // degree-0 node: all s_h==0 -> a_h==0 and 0*inf would NaN; guard:
        if (row1 == row0) r = 0.f;
        out[(size_t)n * 32 + d] = r + 0.25f * (bias[d] + bias[32 + d] + bias[64 + d] + bias[96 + d]);
    }
}

extern "C" void kernel_launch(void* const* d_in, const int* in_sizes, int n_in,
                              void* d_out, int out_size, void* d_ws, size_t ws_size,
                              hipStream_t stream) {
    const float* x      = (const float*)d_in[0];
    const int*   src    = (const int*)d_in[1];
    const int*   dst    = (const int*)d_in[2];
    const float* W      = (const float*)d_in[3];
    const float* attn_l = (const float*)d_in[4];
    const float* attn_r = (const float*)d_in[5];
    const float* bias   = (const float*)d_in[6];
    float* out = (float*)d_out;

    int N = in_sizes[0] / IN_CH;   // 50000
    int E = in_sizes[1];           // 800000

    char* w = (char*)d_ws;
    float* feat     = (float*)w;  w += (size_t)N * 128 * 4;  // 25.6 MB
    float* el       = (float*)w;  w += (size_t)N * 4 * 4;    //  0.8 MB
    float* er       = (float*)w;  w += (size_t)N * 4 * 4;    //  0.8 MB
    int*   deg      = (int*)w;    w += (size_t)N * 4;        //  0.2 MB
    int*   rowstart = (int*)w;    w += (size_t)(N + 1) * 4;  //  0.2 MB
    int*   cursor   = (int*)w;    w += (size_t)N * 4;        //  0.2 MB
    int*   esrc     = (int*)w;    w += (size_t)E * 4;        //  3.2 MB

    hipMemsetAsync(deg, 0, (size_t)N * 4, stream);
    k_deg<<<(E + 255) / 256, 256, 0, stream>>>(dst, deg, E);
    k_scan<<<1, 1024, 0, stream>>>(deg, rowstart, cursor, N);
    k_gemm<<<N / 16, 256, 0, stream>>>(x, W, feat);
    k_elr<<<(N * 4 + 255) / 256, 256, 0, stream>>>(feat, attn_l, attn_r, el, er, N * 4);
    k_scatter<<<(E + 255) / 256, 256, 0, stream>>>(src, dst, cursor, esrc, E);
    k_node<<<(N + 3) / 4, 256, 0, stream>>>(rowstart, esrc, el, er, feat, bias, out, N);
}

// Round 4
// 284.066 us; speedup vs baseline: 1.4339x; 1.4339x over previous
//
#include <hip/hip_runtime.h>

#define IN_CH 128
#define NEG_SLOPE 0.2f

// ---------------- feat = x @ W  (fp32 vector GEMM, W in LDS) ----------------
// Each thread: 2 rows x 4 cols. Block 256 -> 16 rows. grid = N/16 = 3125.
__global__ __launch_bounds__(256) void k_gemm(const float* __restrict__ x,
                                              const float* __restrict__ W,
                                              float* __restrict__ feat) {
    __shared__ float Wl[128 * 128];
#pragma unroll
    for (int i = 0; i < 16; ++i) {
        ((float4*)Wl)[threadIdx.x + 256 * i] = ((const float4*)W)[threadIdx.x + 256 * i];
    }
    __syncthreads();
    int grp = threadIdx.x >> 5;
    int c4 = (threadIdx.x & 31) * 4;
    int r0 = blockIdx.x * 16 + grp * 2;
    const float* xa = x + (size_t)r0 * 128;
    const float* xb = xa + 128;
    float4 acc0 = {0.f, 0.f, 0.f, 0.f};
    float4 acc1 = {0.f, 0.f, 0.f, 0.f};
    for (int k8 = 0; k8 < 128; k8 += 8) {
        float4 a0 = *(const float4*)(xa + k8);
        float4 a1 = *(const float4*)(xa + k8 + 4);
        float4 b0 = *(const float4*)(xb + k8);
        float4 b1 = *(const float4*)(xb + k8 + 4);
        float av[8] = {a0.x, a0.y, a0.z, a0.w, a1.x, a1.y, a1.z, a1.w};
        float bv[8] = {b0.x, b0.y, b0.z, b0.w, b1.x, b1.y, b1.z, b1.w};
#pragma unroll
        for (int j = 0; j < 8; ++j) {
            float4 wv = *(const float4*)(Wl + (k8 + j) * 128 + c4);
            acc0.x += av[j] * wv.x; acc0.y += av[j] * wv.y;
            acc0.z += av[j] * wv.z; acc0.w += av[j] * wv.w;
            acc1.x += bv[j] * wv.x; acc1.y += bv[j] * wv.y;
            acc1.z += bv[j] * wv.z; acc1.w += bv[j] * wv.w;
        }
    }
    *(float4*)(feat + (size_t)r0 * 128 + c4) = acc0;
    *(float4*)(feat + (size_t)(r0 + 1) * 128 + c4) = acc1;
}

// ---------------- el/er: per-(node,head) dot with attn vectors ----------------
__global__ void k_elr(const float* __restrict__ feat,
                      const float* __restrict__ attn_l,
                      const float* __restrict__ attn_r,
                      float* __restrict__ el, float* __restrict__ er, int n4) {
    int idx = blockIdx.x * 256 + threadIdx.x;
    if (idx >= n4) return;
    int n = idx >> 2, h = idx & 3;
    const float4* f4 = (const float4*)(feat + (size_t)n * 128 + h * 32);
    const float4* al = (const float4*)(attn_l + h * 32);
    const float4* ar = (const float4*)(attn_r + h * 32);
    float sl = 0.f, sr = 0.f;
#pragma unroll
    for (int j = 0; j < 8; ++j) {
        float4 fv = f4[j];
        float4 lv = al[j];
        float4 rv = ar[j];
        sl += fv.x * lv.x + fv.y * lv.y + fv.z * lv.z + fv.w * lv.w;
        sr += fv.x * rv.x + fv.y * rv.y + fv.z * rv.z + fv.w * rv.w;
    }
    el[idx] = sl;
    er[idx] = sr;
}

// ---------------- CSR build: histogram -> hierarchical scan -> scatter ----------------
__global__ void k_deg(const int* __restrict__ dst, int* __restrict__ deg, int E) {
    int e = blockIdx.x * 256 + threadIdx.x;
    if (e < E) atomicAdd(&deg[dst[e]], 1);
}

// Stage 1: 49 blocks x 256 threads; each thread sums 4 deg entries -> blocksum[b].
__global__ __launch_bounds__(256) void k_partsum(const int* __restrict__ deg,
                                                 int* __restrict__ blocksum, int N) {
    int base = blockIdx.x * 1024 + threadIdx.x * 4;
    int s = 0;
    if (base + 3 < N) {
        int4 v = *(const int4*)(deg + base);
        s = v.x + v.y + v.z + v.w;
    } else {
        for (int i = 0; i < 4; ++i)
            if (base + i < N) s += deg[base + i];
    }
#pragma unroll
    for (int off = 32; off; off >>= 1) s += __shfl_down(s, off);
    __shared__ int red[4];
    if ((threadIdx.x & 63) == 0) red[threadIdx.x >> 6] = s;
    __syncthreads();
    if (threadIdx.x == 0) blocksum[blockIdx.x] = red[0] + red[1] + red[2] + red[3];
}

// Stage 2: one wave scans NB (<=64) block sums -> blockoff[0..NB] (exclusive, +total at NB).
__global__ __launch_bounds__(64) void k_scanblocks(const int* __restrict__ blocksum,
                                                   int* __restrict__ blockoff, int NB) {
    int t = threadIdx.x;
    int v = (t < NB) ? blocksum[t] : 0;
#pragma unroll
    for (int off = 1; off < 64; off <<= 1) {
        int u = __shfl_up(v, off);
        if (t >= off) v += u;
    }
    if (t < NB) blockoff[t + 1] = v;
    if (t == 0) blockoff[0] = 0;
}

// Stage 3: 49 blocks re-read their 1024 deg entries, in-block exclusive scan,
// add blockoff[b], write rowstart + cursor. Block 0 thread 0 writes rowstart[N].
__global__ __launch_bounds__(256) void k_scanwrite(const int* __restrict__ deg,
                                                   const int* __restrict__ blockoff,
                                                   int* __restrict__ rowstart,
                                                   int* __restrict__ cursor, int N, int NB) {
    int base = blockIdx.x * 1024 + threadIdx.x * 4;
    int v[4];
    int s = 0;
#pragma unroll
    for (int i = 0; i < 4; ++i) {
        v[i] = (base + i < N) ? deg[base + i] : 0;
        s += v[i];
    }
    int lane = threadIdx.x & 63, wid = threadIdx.x >> 6;
    int inc = s;
#pragma unroll
    for (int off = 1; off < 64; off <<= 1) {
        int u = __shfl_up(inc, off);
        if (lane >= off) inc += u;
    }
    __shared__ int wsum[4];
    if (lane == 63) wsum[wid] = inc;
    __syncthreads();
    int woff = 0;
    for (int i = 0; i < wid; ++i) woff += wsum[i];
    int run = blockoff[blockIdx.x] + woff + (inc - s);
#pragma unroll
    for (int i = 0; i < 4; ++i) {
        int id = base + i;
        if (id < N) {
            rowstart[id] = run;
            cursor[id] = run;
            run += v[i];
        }
    }
    if (blockIdx.x == 0 && threadIdx.x == 0) rowstart[N] = blockoff[NB];
}

__global__ void k_scatter(const int* __restrict__ src, const int* __restrict__ dst,
                          int* __restrict__ cursor, int* __restrict__ esrc, int E) {
    int e = blockIdx.x * 256 + threadIdx.x;
    if (e >= E) return;
    int p = atomicAdd(&cursor[dst[e]], 1);
    esrc[p] = src[e];
}

// ---------------- fused per-node softmax + aggregation (no atomics) ----------------
// One 64-lane wave per node. lane = 32*half + d. Single edge loop accumulates
// per-head exp-sums s_h and unnormalized per-head feature sums a_h; final
// out[n,d] = sum_h a_h * (0.25/s_h) + mean_h bias[h,d].
__global__ __launch_bounds__(256) void k_node(const int* __restrict__ rowstart,
                                              const int* __restrict__ esrc,
                                              const float* __restrict__ el,
                                              const float* __restrict__ er,
                                              const float* __restrict__ feat,
                                              const float* __restrict__ bias,
                                              float* __restrict__ out, int N) {
    int n = blockIdx.x * 4 + (threadIdx.x >> 6);
    if (n >= N) return;
    int lane = threadIdx.x & 63;
    int d = lane & 31;
    int half = lane >> 5;
    int row0 = rowstart[n], row1 = rowstart[n + 1];
    const float* erp = er + (size_t)n * 4;
    float er0 = erp[0], er1 = erp[1], er2 = erp[2], er3 = erp[3];
    float s0 = 0.f, s1 = 0.f, s2 = 0.f, s3 = 0.f;
    float a0 = 0.f, a1 = 0.f, a2 = 0.f, a3 = 0.f;
    for (int j = row0 + half; j < row1; j += 2) {
        int sn = esrc[j];
        const float* elp = el + (size_t)sn * 4;
        float t0 = elp[0] + er0;
        float t1 = elp[1] + er1;
        float t2 = elp[2] + er2;
        float t3 = elp[3] + er3;
        float e0 = __expf(t0 > 0.f ? t0 : NEG_SLOPE * t0);
        float e1 = __expf(t1 > 0.f ? t1 : NEG_SLOPE * t1);
        float e2 = __expf(t2 > 0.f ? t2 : NEG_SLOPE * t2);
        float e3 = __expf(t3 > 0.f ? t3 : NEG_SLOPE * t3);
        s0 += e0; s1 += e1; s2 += e2; s3 += e3;
        const float* f = feat + (size_t)sn * 128 + d;
        a0 += e0 * f[0];
        a1 += e1 * f[32];
        a2 += e2 * f[64];
        a3 += e3 * f[96];
    }
    s0 += __shfl_xor(s0, 32); s1 += __shfl_xor(s1, 32);
    s2 += __shfl_xor(s2, 32); s3 += __shfl_xor(s3, 32);
    a0 += __shfl_xor(a0, 32); a1 += __shfl_xor(a1, 32);
    a2 += __shfl_xor(a2, 32); a3 += __shfl_xor(a3, 32);
    if (lane < 32) {
        float r = a0 * (0.25f / s0) + a1 * (0.25f / s1) +
                  a2 * (0.25f / s2) + a3 * (0.25f / s3);
        if (row1 == row0) r = 0.f;   // degree-0 guard (0*inf -> NaN)
        out[(size_t)n * 32 + d] = r + 0.25f * (bias[d] + bias[32 + d] + bias[64 + d] + bias[96 + d]);
    }
}

extern "C" void kernel_launch(void* const* d_in, const int* in_sizes, int n_in,
                              void* d_out, int out_size, void* d_ws, size_t ws_size,
                              hipStream_t stream) {
    const float* x      = (const float*)d_in[0];
    const int*   src    = (const int*)d_in[1];
    const int*   dst    = (const int*)d_in[2];
    const float* W      = (const float*)d_in[3];
    const float* attn_l = (const float*)d_in[4];
    const float* attn_r = (const float*)d_in[5];
    const float* bias   = (const float*)d_in[6];
    float* out = (float*)d_out;

    int N = in_sizes[0] / IN_CH;   // 50000
    int E = in_sizes[1];           // 800000
    int NB = (N + 1023) / 1024;    // 49

    char* w = (char*)d_ws;
    float* feat     = (float*)w;  w += (size_t)N * 128 * 4;  // 25.6 MB
    float* el       = (float*)w;  w += (size_t)N * 4 * 4;    //  0.8 MB
    float* er       = (float*)w;  w += (size_t)N * 4 * 4;    //  0.8 MB
    int*   deg      = (int*)w;    w += (size_t)N * 4;        //  0.2 MB
    int*   rowstart = (int*)w;    w += (size_t)(N + 1) * 4;  //  0.2 MB
    int*   cursor   = (int*)w;    w += (size_t)N * 4;        //  0.2 MB
    int*   esrc     = (int*)w;    w += (size_t)E * 4;        //  3.2 MB
    int*   blocksum = (int*)w;    w += 64 * 4;
    int*   blockoff = (int*)w;    w += 65 * 4;

    hipMemsetAsync(deg, 0, (size_t)N * 4, stream);
    k_deg<<<(E + 255) / 256, 256, 0, stream>>>(dst, deg, E);
    k_partsum<<<NB, 256, 0, stream>>>(deg, blocksum, N);
    k_scanblocks<<<1, 64, 0, stream>>>(blocksum, blockoff, NB);
    k_scanwrite<<<NB, 256, 0, stream>>>(deg, blockoff, rowstart, cursor, N, NB);
    k_gemm<<<N / 16, 256, 0, stream>>>(x, W, feat);
    k_elr<<<(N * 4 + 255) / 256, 256, 0, stream>>>(feat, attn_l, attn_r, el, er, N * 4);
    k_scatter<<<(E + 255) / 256, 256, 0, stream>>>(src, dst, cursor, esrc, E);
    k_node<<<(N + 3) / 4, 256, 0, stream>>>(rowstart, esrc, el, er, feat, bias, out, N);
}

// Round 5
// 228.412 us; speedup vs baseline: 1.7832x; 1.2437x over previous
//
#include <hip/hip_runtime.h>

#define IN_CH 128
#define NEG_SLOPE 0.2f

// fp32 -> bf16 round-to-nearest-even
static __device__ __forceinline__ unsigned short f2bf(float f) {
    union { float f; unsigned int u; } a; a.f = f;
    unsigned int u = a.u;
    u += 0x7fffu + ((u >> 16) & 1u);
    return (unsigned short)(u >> 16);
}

// ---------------- GEMM + fused el/er + bf16 feat store ----------------
// W in LDS. 4 rows x 4 cols per thread; block 256 -> 32 rows. grid = ceil(N/32).
// Epilogue: el/er via 8-lane shfl reduce (fp32, pre-quantization); feat stored bf16.
__global__ __launch_bounds__(256) void k_gemm(const float* __restrict__ x,
                                              const float* __restrict__ W,
                                              const float* __restrict__ attn_l,
                                              const float* __restrict__ attn_r,
                                              unsigned short* __restrict__ featb,
                                              float* __restrict__ el,
                                              float* __restrict__ er, int N) {
    __shared__ float Wl[128 * 128];
#pragma unroll
    for (int i = 0; i < 16; ++i)
        ((float4*)Wl)[threadIdx.x + 256 * i] = ((const float4*)W)[threadIdx.x + 256 * i];
    __syncthreads();
    int grp = threadIdx.x >> 5;
    int l32 = threadIdx.x & 31;
    int c4 = l32 * 4;
    int r0 = blockIdx.x * 32 + grp * 4;
    const float* xp[4];
#pragma unroll
    for (int i = 0; i < 4; ++i) {
        int r = r0 + i; if (r > N - 1) r = N - 1;   // clamp loads for tail block
        xp[i] = x + (size_t)r * 128;
    }
    float4 acc[4] = {{0,0,0,0},{0,0,0,0},{0,0,0,0},{0,0,0,0}};
    for (int k8 = 0; k8 < 128; k8 += 8) {
        float a[4][8];
#pragma unroll
        for (int i = 0; i < 4; ++i) {
            float4 u = *(const float4*)(xp[i] + k8);
            float4 v = *(const float4*)(xp[i] + k8 + 4);
            a[i][0] = u.x; a[i][1] = u.y; a[i][2] = u.z; a[i][3] = u.w;
            a[i][4] = v.x; a[i][5] = v.y; a[i][6] = v.z; a[i][7] = v.w;
        }
#pragma unroll
        for (int j = 0; j < 8; ++j) {
            float4 wv = *(const float4*)(Wl + (k8 + j) * 128 + c4);
#pragma unroll
            for (int i = 0; i < 4; ++i) {
                acc[i].x += a[i][j] * wv.x;
                acc[i].y += a[i][j] * wv.y;
                acc[i].z += a[i][j] * wv.z;
                acc[i].w += a[i][j] * wv.w;
            }
        }
    }
    // attn vectors: flat index over 128 cols == head-major layout
    float4 alv = *(const float4*)(attn_l + c4);
    float4 arv = *(const float4*)(attn_r + c4);
    int h = l32 >> 3;
#pragma unroll
    for (int i = 0; i < 4; ++i) {
        int r = r0 + i;
        float pl = acc[i].x * alv.x + acc[i].y * alv.y + acc[i].z * alv.z + acc[i].w * alv.w;
        float pr = acc[i].x * arv.x + acc[i].y * arv.y + acc[i].z * arv.z + acc[i].w * arv.w;
        pl += __shfl_xor(pl, 1); pl += __shfl_xor(pl, 2); pl += __shfl_xor(pl, 4);
        pr += __shfl_xor(pr, 1); pr += __shfl_xor(pr, 2); pr += __shfl_xor(pr, 4);
        if (r < N) {
            if ((threadIdx.x & 7) == 0) { el[r * 4 + h] = pl; er[r * 4 + h] = pr; }
            ushort4 pk;
            pk.x = f2bf(acc[i].x); pk.y = f2bf(acc[i].y);
            pk.z = f2bf(acc[i].z); pk.w = f2bf(acc[i].w);
            *(ushort4*)(featb + (size_t)r * 128 + c4) = pk;
        }
    }
}

// ---------------- CSR build: rank-trick (one atomic pass total) ----------------
__global__ void k_rank(const int* __restrict__ dst, int* __restrict__ cnt,
                       int* __restrict__ rank, int E) {
    int e = blockIdx.x * 256 + threadIdx.x;
    if (e < E) rank[e] = atomicAdd(&cnt[dst[e]], 1);
}

// Stage 1: 49 blocks; each thread sums 4 cnt entries -> blocksum[b].
__global__ __launch_bounds__(256) void k_partsum(const int* __restrict__ cnt,
                                                 int* __restrict__ blocksum, int N) {
    int base = blockIdx.x * 1024 + threadIdx.x * 4;
    int s = 0;
    if (base + 3 < N) {
        int4 v = *(const int4*)(cnt + base);
        s = v.x + v.y + v.z + v.w;
    } else {
        for (int i = 0; i < 4; ++i)
            if (base + i < N) s += cnt[base + i];
    }
#pragma unroll
    for (int off = 32; off; off >>= 1) s += __shfl_down(s, off);
    __shared__ int red[4];
    if ((threadIdx.x & 63) == 0) red[threadIdx.x >> 6] = s;
    __syncthreads();
    if (threadIdx.x == 0) blocksum[blockIdx.x] = red[0] + red[1] + red[2] + red[3];
}

// Stage 2: one wave scans NB (<=64) block sums -> blockoff[0..NB].
__global__ __launch_bounds__(64) void k_scanblocks(const int* __restrict__ blocksum,
                                                   int* __restrict__ blockoff, int NB) {
    int t = threadIdx.x;
    int v = (t < NB) ? blocksum[t] : 0;
#pragma unroll
    for (int off = 1; off < 64; off <<= 1) {
        int u = __shfl_up(v, off);
        if (t >= off) v += u;
    }
    if (t < NB) blockoff[t + 1] = v;
    if (t == 0) blockoff[0] = 0;
}

// Stage 3: in-block exclusive scan + blockoff -> rowstart.
__global__ __launch_bounds__(256) void k_scanwrite(const int* __restrict__ cnt,
                                                   const int* __restrict__ blockoff,
                                                   int* __restrict__ rowstart, int N, int NB) {
    int base = blockIdx.x * 1024 + threadIdx.x * 4;
    int v[4];
    int s = 0;
#pragma unroll
    for (int i = 0; i < 4; ++i) {
        v[i] = (base + i < N) ? cnt[base + i] : 0;
        s += v[i];
    }
    int lane = threadIdx.x & 63, wid = threadIdx.x >> 6;
    int inc = s;
#pragma unroll
    for (int off = 1; off < 64; off <<= 1) {
        int u = __shfl_up(inc, off);
        if (lane >= off) inc += u;
    }
    __shared__ int wsum[4];
    if (lane == 63) wsum[wid] = inc;
    __syncthreads();
    int woff = 0;
    for (int i = 0; i < wid; ++i) woff += wsum[i];
    int run = blockoff[blockIdx.x] + woff + (inc - s);
#pragma unroll
    for (int i = 0; i < 4; ++i) {
        int id = base + i;
        if (id < N) {
            rowstart[id] = run;
            run += v[i];
        }
    }
    if (blockIdx.x == 0 && threadIdx.x == 0) rowstart[N] = blockoff[NB];
}

// Place edges without atomics: position = rowstart[dst] + rank.
__global__ void k_place(const int* __restrict__ src, const int* __restrict__ dst,
                        const int* __restrict__ rank, const int* __restrict__ rowstart,
                        int* __restrict__ esrc, int E) {
    int e = blockIdx.x * 256 + threadIdx.x;
    if (e >= E) return;
    esrc[rowstart[dst[e]] + rank[e]] = src[e];
}

// ---------------- fused per-node softmax + aggregation ----------------
// One wave per node; lane = 32*half + d8. Lane owns dims 4*d8..4*d8+3 of head d8>>3:
// one uint2 (4xbf16) gather + ONE exp per lane per edge. Halves split edges by parity.
__global__ __launch_bounds__(256) void k_node(const int* __restrict__ rowstart,
                                              const int* __restrict__ esrc,
                                              const float* __restrict__ el,
                                              const float* __restrict__ er,
                                              const unsigned short* __restrict__ featb,
                                              const float* __restrict__ bias,
                                              float* __restrict__ out, int N) {
    int n = blockIdx.x * 4 + (threadIdx.x >> 6);
    if (n >= N) return;
    int lane = threadIdx.x & 63;
    int half = lane >> 5;
    int d8 = lane & 31;
    int h = d8 >> 3;
    int row0 = rowstart[n], row1 = rowstart[n + 1];
    float erh = er[(size_t)n * 4 + h];
    float s = 0.f;
    float ax = 0.f, ay = 0.f, az = 0.f, aw = 0.f;
    for (int j = row0 + half; j < row1; j += 2) {
        int sn = esrc[j];
        float t = el[(size_t)sn * 4 + h] + erh;
        float e = __expf(t > 0.f ? t : NEG_SLOPE * t);
        s += e;
        uint2 q = *(const uint2*)(featb + (size_t)sn * 128 + d8 * 4);
        float f0 = __uint_as_float(q.x << 16);
        float f1 = __uint_as_float(q.x & 0xffff0000u);
        float f2 = __uint_as_float(q.y << 16);
        float f3 = __uint_as_float(q.y & 0xffff0000u);
        ax += e * f0; ay += e * f1; az += e * f2; aw += e * f3;
    }
    // combine edge-parity halves
    s  += __shfl_xor(s, 32);
    ax += __shfl_xor(ax, 32); ay += __shfl_xor(ay, 32);
    az += __shfl_xor(az, 32); aw += __shfl_xor(aw, 32);
    // per-head normalize (deg-0 guard: contribute 0)
    float inv = (row1 > row0) ? 0.25f / s : 0.f;
    ax *= inv; ay *= inv; az *= inv; aw *= inv;
    // sum over the 4 heads: lanes d8, d8^8, d8^16 hold same dims, different heads
    ax += __shfl_xor(ax, 8);  ay += __shfl_xor(ay, 8);
    az += __shfl_xor(az, 8);  aw += __shfl_xor(aw, 8);
    ax += __shfl_xor(ax, 16); ay += __shfl_xor(ay, 16);
    az += __shfl_xor(az, 16); aw += __shfl_xor(aw, 16);
    if (lane < 8) {
        int dd = lane * 4;
        float4 o;
        o.x = ax + 0.25f * (bias[dd]     + bias[32 + dd]     + bias[64 + dd]     + bias[96 + dd]);
        o.y = ay + 0.25f * (bias[dd + 1] + bias[33 + dd]     + bias[65 + dd]     + bias[97 + dd]);
        o.z = az + 0.25f * (bias[dd + 2] + bias[34 + dd]     + bias[66 + dd]     + bias[98 + dd]);
        o.w = aw + 0.25f * (bias[dd + 3] + bias[35 + dd]     + bias[67 + dd]     + bias[99 + dd]);
        *(float4*)(out + (size_t)n * 32 + dd) = o;
    }
}

extern "C" void kernel_launch(void* const* d_in, const int* in_sizes, int n_in,
                              void* d_out, int out_size, void* d_ws, size_t ws_size,
                              hipStream_t stream) {
    const float* x      = (const float*)d_in[0];
    const int*   src    = (const int*)d_in[1];
    const int*   dst    = (const int*)d_in[2];
    const float* W      = (const float*)d_in[3];
    const float* attn_l = (const float*)d_in[4];
    const float* attn_r = (const float*)d_in[5];
    const float* bias   = (const float*)d_in[6];
    float* out = (float*)d_out;

    int N = in_sizes[0] / IN_CH;   // 50000
    int E = in_sizes[1];           // 800000
    int NB = (N + 1023) / 1024;    // 49

    char* w = (char*)d_ws;
    unsigned short* featb = (unsigned short*)w; w += (size_t)N * 128 * 2;  // 12.8 MB
    float* el       = (float*)w;  w += (size_t)N * 4 * 4;
    float* er       = (float*)w;  w += (size_t)N * 4 * 4;
    int*   cnt      = (int*)w;    w += (size_t)N * 4;
    int*   rank     = (int*)w;    w += (size_t)E * 4;        // 3.2 MB
    int*   rowstart = (int*)w;    w += (size_t)(N + 1) * 4;
    int*   esrc     = (int*)w;    w += (size_t)E * 4;        // 3.2 MB
    int*   blocksum = (int*)w;    w += 64 * 4;
    int*   blockoff = (int*)w;    w += 65 * 4;

    hipMemsetAsync(cnt, 0, (size_t)N * 4, stream);
    k_rank<<<(E + 255) / 256, 256, 0, stream>>>(dst, cnt, rank, E);
    k_partsum<<<NB, 256, 0, stream>>>(cnt, blocksum, N);
    k_scanblocks<<<1, 64, 0, stream>>>(blocksum, blockoff, NB);
    k_scanwrite<<<NB, 256, 0, stream>>>(cnt, blockoff, rowstart, N, NB);
    k_gemm<<<(N + 31) / 32, 256, 0, stream>>>(x, W, attn_l, attn_r, featb, el, er, N);
    k_place<<<(E + 255) / 256, 256, 0, stream>>>(src, dst, rank, rowstart, esrc, E);
    k_node<<<(N + 3) / 4, 256, 0, stream>>>(rowstart, esrc, el, er, featb, bias, out, N);
}

// Round 6
// 213.163 us; speedup vs baseline: 1.9108x; 1.0715x over previous
//
#include <hip/hip_runtime.h>

#define IN_CH 128
#define NEG_SLOPE 0.2f

// fp32 -> bf16 round-to-nearest-even
static __device__ __forceinline__ unsigned short f2bf(float f) {
    union { float f; unsigned int u; } a; a.f = f;
    unsigned int u = a.u;
    u += 0x7fffu + ((u >> 16) & 1u);
    return (unsigned short)(u >> 16);
}

// ---------------- GEMM + fused el/er + bf16 feat store ----------------
// W in LDS. 4 rows x 4 cols per thread; block 256 -> 32 rows. grid = ceil(N/32).
__global__ __launch_bounds__(256) void k_gemm(const float* __restrict__ x,
                                              const float* __restrict__ W,
                                              const float* __restrict__ attn_l,
                                              const float* __restrict__ attn_r,
                                              unsigned short* __restrict__ featb,
                                              float* __restrict__ el,
                                              float* __restrict__ er, int N) {
    __shared__ float Wl[128 * 128];
#pragma unroll
    for (int i = 0; i < 16; ++i)
        ((float4*)Wl)[threadIdx.x + 256 * i] = ((const float4*)W)[threadIdx.x + 256 * i];
    __syncthreads();
    int grp = threadIdx.x >> 5;
    int l32 = threadIdx.x & 31;
    int c4 = l32 * 4;
    int r0 = blockIdx.x * 32 + grp * 4;
    const float* xp[4];
#pragma unroll
    for (int i = 0; i < 4; ++i) {
        int r = r0 + i; if (r > N - 1) r = N - 1;
        xp[i] = x + (size_t)r * 128;
    }
    float4 acc[4] = {{0,0,0,0},{0,0,0,0},{0,0,0,0},{0,0,0,0}};
    for (int k8 = 0; k8 < 128; k8 += 8) {
        float a[4][8];
#pragma unroll
        for (int i = 0; i < 4; ++i) {
            float4 u = *(const float4*)(xp[i] + k8);
            float4 v = *(const float4*)(xp[i] + k8 + 4);
            a[i][0] = u.x; a[i][1] = u.y; a[i][2] = u.z; a[i][3] = u.w;
            a[i][4] = v.x; a[i][5] = v.y; a[i][6] = v.z; a[i][7] = v.w;
        }
#pragma unroll
        for (int j = 0; j < 8; ++j) {
            float4 wv = *(const float4*)(Wl + (k8 + j) * 128 + c4);
#pragma unroll
            for (int i = 0; i < 4; ++i) {
                acc[i].x += a[i][j] * wv.x;
                acc[i].y += a[i][j] * wv.y;
                acc[i].z += a[i][j] * wv.z;
                acc[i].w += a[i][j] * wv.w;
            }
        }
    }
    float4 alv = *(const float4*)(attn_l + c4);
    float4 arv = *(const float4*)(attn_r + c4);
    int h = l32 >> 3;
#pragma unroll
    for (int i = 0; i < 4; ++i) {
        int r = r0 + i;
        float pl = acc[i].x * alv.x + acc[i].y * alv.y + acc[i].z * alv.z + acc[i].w * alv.w;
        float pr = acc[i].x * arv.x + acc[i].y * arv.y + acc[i].z * arv.z + acc[i].w * arv.w;
        pl += __shfl_xor(pl, 1); pl += __shfl_xor(pl, 2); pl += __shfl_xor(pl, 4);
        pr += __shfl_xor(pr, 1); pr += __shfl_xor(pr, 2); pr += __shfl_xor(pr, 4);
        if (r < N) {
            if ((threadIdx.x & 7) == 0) { el[r * 4 + h] = pl; er[r * 4 + h] = pr; }
            ushort4 pk;
            pk.x = f2bf(acc[i].x); pk.y = f2bf(acc[i].y);
            pk.z = f2bf(acc[i].z); pk.w = f2bf(acc[i].w);
            *(ushort4*)(featb + (size_t)r * 128 + c4) = pk;
        }
    }
}

// ---------------- CSR build: rank-trick (one atomic pass) ----------------
__global__ void k_rank(const int* __restrict__ dst, int* __restrict__ cnt,
                       int* __restrict__ rank, int E) {
    int e = blockIdx.x * 256 + threadIdx.x;
    if (e < E) rank[e] = atomicAdd(&cnt[dst[e]], 1);
}

__global__ __launch_bounds__(256) void k_partsum(const int* __restrict__ cnt,
                                                 int* __restrict__ blocksum, int N) {
    int base = blockIdx.x * 1024 + threadIdx.x * 4;
    int s = 0;
    if (base + 3 < N) {
        int4 v = *(const int4*)(cnt + base);
        s = v.x + v.y + v.z + v.w;
    } else {
        for (int i = 0; i < 4; ++i)
            if (base + i < N) s += cnt[base + i];
    }
#pragma unroll
    for (int off = 32; off; off >>= 1) s += __shfl_down(s, off);
    __shared__ int red[4];
    if ((threadIdx.x & 63) == 0) red[threadIdx.x >> 6] = s;
    __syncthreads();
    if (threadIdx.x == 0) blocksum[blockIdx.x] = red[0] + red[1] + red[2] + red[3];
}

__global__ __launch_bounds__(64) void k_scanblocks(const int* __restrict__ blocksum,
                                                   int* __restrict__ blockoff, int NB) {
    int t = threadIdx.x;
    int v = (t < NB) ? blocksum[t] : 0;
#pragma unroll
    for (int off = 1; off < 64; off <<= 1) {
        int u = __shfl_up(v, off);
        if (t >= off) v += u;
    }
    if (t < NB) blockoff[t + 1] = v;
    if (t == 0) blockoff[0] = 0;
}

__global__ __launch_bounds__(256) void k_scanwrite(const int* __restrict__ cnt,
                                                   const int* __restrict__ blockoff,
                                                   int* __restrict__ rowstart, int N, int NB) {
    int base = blockIdx.x * 1024 + threadIdx.x * 4;
    int v[4];
    int s = 0;
#pragma unroll
    for (int i = 0; i < 4; ++i) {
        v[i] = (base + i < N) ? cnt[base + i] : 0;
        s += v[i];
    }
    int lane = threadIdx.x & 63, wid = threadIdx.x >> 6;
    int inc = s;
#pragma unroll
    for (int off = 1; off < 64; off <<= 1) {
        int u = __shfl_up(inc, off);
        if (lane >= off) inc += u;
    }
    __shared__ int wsum[4];
    if (lane == 63) wsum[wid] = inc;
    __syncthreads();
    int woff = 0;
    for (int i = 0; i < wid; ++i) woff += wsum[i];
    int run = blockoff[blockIdx.x] + woff + (inc - s);
#pragma unroll
    for (int i = 0; i < 4; ++i) {
        int id = base + i;
        if (id < N) {
            rowstart[id] = run;
            run += v[i];
        }
    }
    if (blockIdx.x == 0 && threadIdx.x == 0) rowstart[N] = blockoff[NB];
}

__global__ void k_place(const int* __restrict__ src, const int* __restrict__ dst,
                        const int* __restrict__ rank, const int* __restrict__ rowstart,
                        int* __restrict__ esrc, int E) {
    int e = blockIdx.x * 256 + threadIdx.x;
    if (e >= E) return;
    esrc[rowstart[dst[e]] + rank[e]] = src[e];
}

// ---------------- fused per-node softmax + aggregation ----------------
// One wave per node. 16 lanes per edge (lane owns 8 dims via uint4), 4 edges
// in flight per wave-iteration. lane = 16*g + r; head h = r>>2.
__global__ __launch_bounds__(256) void k_node(const int* __restrict__ rowstart,
                                              const int* __restrict__ esrc,
                                              const float* __restrict__ el,
                                              const float* __restrict__ er,
                                              const unsigned short* __restrict__ featb,
                                              const float* __restrict__ bias,
                                              float* __restrict__ out, int N) {
    int n = blockIdx.x * 4 + (threadIdx.x >> 6);
    if (n >= N) return;
    int lane = threadIdx.x & 63;
    int g = lane >> 4;      // edge group 0..3
    int r = lane & 15;      // dim-lane within edge: dims 8r..8r+7
    int h = r >> 2;         // head
    int row0 = rowstart[n], row1 = rowstart[n + 1];
    float erh = er[(size_t)n * 4 + h];
    float s = 0.f;
    float a0 = 0.f, a1 = 0.f, a2 = 0.f, a3 = 0.f;
    float a4 = 0.f, a5 = 0.f, a6 = 0.f, a7 = 0.f;
    for (int j = row0 + g; j < row1; j += 4) {
        int sn = esrc[j];
        float t = el[(size_t)sn * 4 + h] + erh;
        float e = __expf(t > 0.f ? t : NEG_SLOPE * t);
        s += e;
        uint4 q = *(const uint4*)(featb + (size_t)sn * 128 + r * 8);
        a0 += e * __uint_as_float(q.x << 16);
        a1 += e * __uint_as_float(q.x & 0xffff0000u);
        a2 += e * __uint_as_float(q.y << 16);
        a3 += e * __uint_as_float(q.y & 0xffff0000u);
        a4 += e * __uint_as_float(q.z << 16);
        a5 += e * __uint_as_float(q.z & 0xffff0000u);
        a6 += e * __uint_as_float(q.w << 16);
        a7 += e * __uint_as_float(q.w & 0xffff0000u);
    }
    // combine the 4 edge groups (lanes r, r+16, r+32, r+48)
    s  += __shfl_xor(s, 16);  s  += __shfl_xor(s, 32);
    a0 += __shfl_xor(a0, 16); a0 += __shfl_xor(a0, 32);
    a1 += __shfl_xor(a1, 16); a1 += __shfl_xor(a1, 32);
    a2 += __shfl_xor(a2, 16); a2 += __shfl_xor(a2, 32);
    a3 += __shfl_xor(a3, 16); a3 += __shfl_xor(a3, 32);
    a4 += __shfl_xor(a4, 16); a4 += __shfl_xor(a4, 32);
    a5 += __shfl_xor(a5, 16); a5 += __shfl_xor(a5, 32);
    a6 += __shfl_xor(a6, 16); a6 += __shfl_xor(a6, 32);
    a7 += __shfl_xor(a7, 16); a7 += __shfl_xor(a7, 32);
    // per-head normalize (deg-0 guard)
    float inv = (row1 > row0) ? 0.25f / s : 0.f;
    a0 *= inv; a1 *= inv; a2 *= inv; a3 *= inv;
    a4 *= inv; a5 *= inv; a6 *= inv; a7 *= inv;
    // sum over 4 heads: lanes r, r^4, r^8, r^12 hold same in-head dims
    a0 += __shfl_xor(a0, 4); a0 += __shfl_xor(a0, 8);
    a1 += __shfl_xor(a1, 4); a1 += __shfl_xor(a1, 8);
    a2 += __shfl_xor(a2, 4); a2 += __shfl_xor(a2, 8);
    a3 += __shfl_xor(a3, 4); a3 += __shfl_xor(a3, 8);
    a4 += __shfl_xor(a4, 4); a4 += __shfl_xor(a4, 8);
    a5 += __shfl_xor(a5, 4); a5 += __shfl_xor(a5, 8);
    a6 += __shfl_xor(a6, 4); a6 += __shfl_xor(a6, 8);
    a7 += __shfl_xor(a7, 4); a7 += __shfl_xor(a7, 8);
    if (lane < 4) {
        int dd = lane * 8;   // output dims dd..dd+7
        float4 o0, o1;
        o0.x = a0 + 0.25f * (bias[dd + 0] + bias[32 + dd + 0] + bias[64 + dd + 0] + bias[96 + dd + 0]);
        o0.y = a1 + 0.25f * (bias[dd + 1] + bias[32 + dd + 1] + bias[64 + dd + 1] + bias[96 + dd + 1]);
        o0.z = a2 + 0.25f * (bias[dd + 2] + bias[32 + dd + 2] + bias[64 + dd + 2] + bias[96 + dd + 2]);
        o0.w = a3 + 0.25f * (bias[dd + 3] + bias[32 + dd + 3] + bias[64 + dd + 3] + bias[96 + dd + 3]);
        o1.x = a4 + 0.25f * (bias[dd + 4] + bias[32 + dd + 4] + bias[64 + dd + 4] + bias[96 + dd + 4]);
        o1.y = a5 + 0.25f * (bias[dd + 5] + bias[32 + dd + 5] + bias[64 + dd + 5] + bias[96 + dd + 5]);
        o1.z = a6 + 0.25f * (bias[dd + 6] + bias[32 + dd + 6] + bias[64 + dd + 6] + bias[96 + dd + 6]);
        o1.w = a7 + 0.25f * (bias[dd + 7] + bias[32 + dd + 7] + bias[64 + dd + 7] + bias[96 + dd + 7]);
        *(float4*)(out + (size_t)n * 32 + dd) = o0;
        *(float4*)(out + (size_t)n * 32 + dd + 4) = o1;
    }
}

extern "C" void kernel_launch(void* const* d_in, const int* in_sizes, int n_in,
                              void* d_out, int out_size, void* d_ws, size_t ws_size,
                              hipStream_t stream) {
    const float* x      = (const float*)d_in[0];
    const int*   src    = (const int*)d_in[1];
    const int*   dst    = (const int*)d_in[2];
    const float* W      = (const float*)d_in[3];
    const float* attn_l = (const float*)d_in[4];
    const float* attn_r = (const float*)d_in[5];
    const float* bias   = (const float*)d_in[6];
    float* out = (float*)d_out;

    int N = in_sizes[0] / IN_CH;   // 50000
    int E = in_sizes[1];           // 800000
    int NB = (N + 1023) / 1024;    // 49

    char* w = (char*)d_ws;
    unsigned short* featb = (unsigned short*)w; w += (size_t)N * 128 * 2;
    float* el       = (float*)w;  w += (size_t)N * 4 * 4;
    float* er       = (float*)w;  w += (size_t)N * 4 * 4;
    int*   cnt      = (int*)w;    w += (size_t)N * 4;
    int*   rank     = (int*)w;    w += (size_t)E * 4;
    int*   rowstart = (int*)w;    w += (size_t)(N + 1) * 4;
    int*   esrc     = (int*)w;    w += (size_t)E * 4;
    int*   blocksum = (int*)w;    w += 64 * 4;
    int*   blockoff = (int*)w;    w += 65 * 4;

    hipMemsetAsync(cnt, 0, (size_t)N * 4, stream);
    k_rank<<<(E + 255) / 256, 256, 0, stream>>>(dst, cnt, rank, E);
    k_partsum<<<NB, 256, 0, stream>>>(cnt, blocksum, N);
    k_scanblocks<<<1, 64, 0, stream>>>(blocksum, blockoff, NB);
    k_scanwrite<<<NB, 256, 0, stream>>>(cnt, blockoff, rowstart, N, NB);
    k_gemm<<<(N + 31) / 32, 256, 0, stream>>>(x, W, attn_l, attn_r, featb, el, er, N);
    k_place<<<(E + 255) / 256, 256, 0, stream>>>(src, dst, rank, rowstart, esrc, E);
    k_node<<<(N + 3) / 4, 256, 0, stream>>>(rowstart, esrc, el, er, featb, bias, out, N);
}